// Round 1
// baseline (371.275 us; speedup 1.0000x reference)
//
#include <hip/hip_runtime.h>

// Single causal attention head: B=16, T=2048, C=1024, H=64.
// Pipeline: pack_w (W fp32 -> bf16, MFMA-B-friendly layout)
//        -> proj (x fp32 -> LDS bf16 -> MFMA -> Q,K,V bf16 in ws; Q pre-scaled by 1/8)
//        -> flash attention (MFMA QK^T + online softmax + MFMA PV), fp32 out.
//
// MFMA 16x16x32 bf16 layouts (HW-verified facts from guide):
//   A[m][k]: m = lane&15, k = (lane>>4)*8 + j   (8 contiguous bf16 -> 16B load)
//   B[k][n]: n = lane&15, k = (lane>>4)*8 + j
//   C/D:     col = lane&15, row = (lane>>4)*4 + reg

typedef float  floatx4 __attribute__((ext_vector_type(4)));
typedef __bf16 bf16x8  __attribute__((ext_vector_type(8)));
typedef short  short8v __attribute__((ext_vector_type(8)));

constexpr int Bn = 16;
constexpr int Tn = 2048;
constexpr int Cn = 1024;
constexpr int Hn = 64;
constexpr int BT = Bn * Tn;   // 32768 rows

// fp32 -> bf16, round-to-nearest-even
__device__ __forceinline__ unsigned short f2b(float f) {
  unsigned int u = __builtin_bit_cast(unsigned int, f);
  u += 0x7fffu + ((u >> 16) & 1u);
  return (unsigned short)(u >> 16);
}

// ---------------------------------------------------------------------------
// Pack Wq|Wk|Wv (each [1024][64] fp32) into bf16 with layout
// Wp[mat*4+ct][kb][c][j]  (ct = 16-col tile, kb = k/8, c = col in tile, j = k&7)
// so a B-fragment is one 16B contiguous load.
// ---------------------------------------------------------------------------
__global__ __launch_bounds__(256) void pack_w(const float* __restrict__ Wq,
                                              const float* __restrict__ Wk,
                                              const float* __restrict__ Wv,
                                              unsigned short* __restrict__ Wp) {
  int gid = blockIdx.x * 256 + threadIdx.x;       // 3*1024*64 = 196608 total
  int mat = gid >> 16;                            // 0..2
  int rem = gid & 65535;
  int k   = rem >> 6;                             // 0..1023
  int col = rem & 63;                             // 0..63
  const float* W = (mat == 0) ? Wq : (mat == 1) ? Wk : Wv;
  float v = W[rem];
  int kb = k >> 3, j = k & 7, ct = col >> 4, c = col & 15;
  size_t idx = ((((size_t)(mat * 4 + ct) * 128) + kb) * 16 + c) * 8 + j;
  Wp[idx] = f2b(v);
}

// ---------------------------------------------------------------------------
// QKV projection: [BT x 1024] fp32 x [1024 x 192] -> Q,K,V bf16 [BT][64].
// Block: 256 threads (4 waves), 64 rows, all 192 output cols.
// Wave w owns rows [w*16, w*16+16); 12 col-tiles of 16; K-loop BK=32.
// ---------------------------------------------------------------------------
__global__ __launch_bounds__(256) void proj_kernel(
    const float* __restrict__ x, const unsigned short* __restrict__ Wp,
    unsigned short* __restrict__ Q, unsigned short* __restrict__ K,
    unsigned short* __restrict__ V) {
  __shared__ alignas(16) unsigned short xt[64][40];  // stride 40 bf16 = 80B (2-way-free banks)

  const int tid  = threadIdx.x;
  const int wave = tid >> 6;
  const int lane = tid & 63;
  const int quad = lane >> 4;
  const int l16  = lane & 15;
  const int rbase = blockIdx.x * 64;

  floatx4 acc[12];
#pragma unroll
  for (int i = 0; i < 12; ++i) acc[i] = (floatx4){0.f, 0.f, 0.f, 0.f};

  const int sr = tid >> 2;          // staging row 0..63
  const int sc = (tid & 3) * 8;     // staging col 0,8,16,24
  const float* xrow = x + (size_t)(rbase + sr) * Cn + sc;

  for (int k0 = 0; k0 < Cn; k0 += 32) {
    // stage 64x32 fp32 -> bf16 LDS tile
    floatx4 a = *reinterpret_cast<const floatx4*>(xrow + k0);
    floatx4 b = *reinterpret_cast<const floatx4*>(xrow + k0 + 4);
    short8v pv;
    pv[0] = (short)f2b(a[0]); pv[1] = (short)f2b(a[1]);
    pv[2] = (short)f2b(a[2]); pv[3] = (short)f2b(a[3]);
    pv[4] = (short)f2b(b[0]); pv[5] = (short)f2b(b[1]);
    pv[6] = (short)f2b(b[2]); pv[7] = (short)f2b(b[3]);
    *reinterpret_cast<short8v*>(&xt[sr][sc]) = pv;
    __syncthreads();

    bf16x8 af = *reinterpret_cast<const bf16x8*>(&xt[wave * 16 + l16][quad * 8]);
    const int kb = (k0 >> 3) + quad;
#pragma unroll
    for (int t = 0; t < 12; ++t) {
      bf16x8 bf = *reinterpret_cast<const bf16x8*>(
          Wp + ((size_t)(t * 128 + kb) * 16 + l16) * 8);
      acc[t] = __builtin_amdgcn_mfma_f32_16x16x32_bf16(af, bf, acc[t], 0, 0, 0);
    }
    __syncthreads();
  }

#pragma unroll
  for (int t = 0; t < 12; ++t) {
    const int mat = t >> 2, ct = t & 3;
    unsigned short* dst = (mat == 0) ? Q : (mat == 1) ? K : V;
    const float scale = (mat == 0) ? 0.125f : 1.0f;  // fold softmax scale into Q
#pragma unroll
    for (int r = 0; r < 4; ++r) {
      int row = rbase + wave * 16 + quad * 4 + r;
      dst[(size_t)row * Hn + ct * 16 + l16] = f2b(acc[t][r] * scale);
    }
  }
}

// ---------------------------------------------------------------------------
// Flash attention. Block = 256 threads (4 waves) handles one (batch, 64-row
// q-tile). Wave w owns q rows [w*16, w*16+16). KV tiles of 64, causal skip.
// ---------------------------------------------------------------------------
__global__ __launch_bounds__(256) void flash_kernel(
    const unsigned short* __restrict__ Q, const unsigned short* __restrict__ K,
    const unsigned short* __restrict__ V, float* __restrict__ out) {
  __shared__ alignas(16) unsigned short Vt[64][72];     // V^T tile [h][s]
  __shared__ alignas(16) unsigned short P[4][16][72];   // per-wave P tile [m][s]

  const int tid  = threadIdx.x;
  const int wave = tid >> 6;
  const int lane = tid & 63;
  const int quad = lane >> 4;
  const int l16  = lane & 15;

  const int b  = blockIdx.x & 15;
  const int qt = 31 - (blockIdx.x >> 4);   // big tiles first for balance
  const int qbase = qt * 64;
  const size_t bbase = (size_t)b * Tn * Hn;

  // Q fragments for this wave's 16 rows (Q pre-scaled by 1/8)
  bf16x8 qf[2];
#pragma unroll
  for (int i = 0; i < 2; ++i)
    qf[i] = *reinterpret_cast<const bf16x8*>(
        &Q[bbase + (size_t)(qbase + wave * 16 + l16) * Hn + i * 32 + quad * 8]);

  floatx4 O[4];
#pragma unroll
  for (int i = 0; i < 4; ++i) O[i] = (floatx4){0.f, 0.f, 0.f, 0.f};
  float m_r[4], l_r[4];
#pragma unroll
  for (int r = 0; r < 4; ++r) { m_r[r] = -INFINITY; l_r[r] = 0.f; }

  const int srow = tid >> 2;          // V staging: source row (s) 0..63
  const int shb  = (tid & 3) * 16;    // h base 0,16,32,48
  unsigned short* VtF = &Vt[0][0];

  for (int kt = 0; kt <= qt; ++kt) {
    const int kvbase = kt * 64;
    __syncthreads();  // previous iter done reading Vt
    {
      const unsigned short* vsrc = &V[bbase + (size_t)(kvbase + srow) * Hn + shb];
      short8v v0 = *reinterpret_cast<const short8v*>(vsrc);
      short8v v1 = *reinterpret_cast<const short8v*>(vsrc + 8);
#pragma unroll
      for (int j = 0; j < 8; ++j) {
        VtF[(shb + j) * 72 + srow]     = (unsigned short)v0[j];
        VtF[(shb + 8 + j) * 72 + srow] = (unsigned short)v1[j];
      }
    }
    __syncthreads();

    // S = Q K^T  (4 col-tiles x 2 k-steps), B-frags straight from global K
    floatx4 S[4];
#pragma unroll
    for (int ct = 0; ct < 4; ++ct) {
      floatx4 s = (floatx4){0.f, 0.f, 0.f, 0.f};
#pragma unroll
      for (int kk = 0; kk < 2; ++kk) {
        bf16x8 bf = *reinterpret_cast<const bf16x8*>(
            &K[bbase + (size_t)(kvbase + ct * 16 + l16) * Hn + kk * 32 + quad * 8]);
        s = __builtin_amdgcn_mfma_f32_16x16x32_bf16(qf[kk], bf, s, 0, 0, 0);
      }
      S[ct] = s;
    }

    // causal mask (only bites on the diagonal tile)
#pragma unroll
    for (int ct = 0; ct < 4; ++ct)
#pragma unroll
      for (int r = 0; r < 4; ++r) {
        int trow = qbase + wave * 16 + quad * 4 + r;
        int scol = kvbase + ct * 16 + l16;
        if (scol > trow) S[ct][r] = -1e30f;
      }

    // online softmax per row (row = quad*4+r, spread over 16 lanes)
#pragma unroll
    for (int r = 0; r < 4; ++r) {
      float mx = fmaxf(fmaxf(S[0][r], S[1][r]), fmaxf(S[2][r], S[3][r]));
#pragma unroll
      for (int d = 1; d < 16; d <<= 1) mx = fmaxf(mx, __shfl_xor(mx, d));
      float mnew  = fmaxf(m_r[r], mx);
      float alpha = __expf(m_r[r] - mnew);
      float rs = 0.f;
#pragma unroll
      for (int ct = 0; ct < 4; ++ct) {
        float p = __expf(S[ct][r] - mnew);
        S[ct][r] = p;
        rs += p;
      }
#pragma unroll
      for (int d = 1; d < 16; d <<= 1) rs += __shfl_xor(rs, d);
      l_r[r] = l_r[r] * alpha + rs;
      m_r[r] = mnew;
#pragma unroll
      for (int ct = 0; ct < 4; ++ct) O[ct][r] *= alpha;
#pragma unroll
      for (int ct = 0; ct < 4; ++ct)
        P[wave][quad * 4 + r][ct * 16 + l16] = f2b(S[ct][r]);
    }
    __syncthreads();  // P write -> P read ordering (uniform trip count)

    // O += P V   (A-frags from P LDS, B-frags from Vt LDS)
    bf16x8 pf[2];
    pf[0] = *reinterpret_cast<const bf16x8*>(&P[wave][l16][quad * 8]);
    pf[1] = *reinterpret_cast<const bf16x8*>(&P[wave][l16][32 + quad * 8]);
#pragma unroll
    for (int ht = 0; ht < 4; ++ht) {
#pragma unroll
      for (int kk = 0; kk < 2; ++kk) {
        bf16x8 vf = *reinterpret_cast<const bf16x8*>(
            &Vt[ht * 16 + l16][kk * 32 + quad * 8]);
        O[ht] = __builtin_amdgcn_mfma_f32_16x16x32_bf16(pf[kk], vf, O[ht], 0, 0, 0);
      }
    }
  }

  // epilogue: out = O / l
#pragma unroll
  for (int r = 0; r < 4; ++r) {
    float inv = 1.0f / l_r[r];
    int trow = qbase + wave * 16 + quad * 4 + r;
#pragma unroll
    for (int ht = 0; ht < 4; ++ht)
      out[bbase + (size_t)trow * Hn + ht * 16 + l16] = O[ht][r] * inv;
  }
}

// ---------------------------------------------------------------------------
extern "C" void kernel_launch(void* const* d_in, const int* in_sizes, int n_in,
                              void* d_out, int out_size, void* d_ws, size_t ws_size,
                              hipStream_t stream) {
  const float* x  = (const float*)d_in[0];
  const float* Wq = (const float*)d_in[1];
  const float* Wk = (const float*)d_in[2];
  const float* Wv = (const float*)d_in[3];
  float* out = (float*)d_out;

  char* ws = (char*)d_ws;
  // ws layout: Q (4MB) | K (4MB) | V (4MB) | Wp (384KB)   -> ~12.4 MB total
  unsigned short* Q  = (unsigned short*)(ws);
  unsigned short* Kb = (unsigned short*)(ws + ((size_t)4 << 20));
  unsigned short* Vb = (unsigned short*)(ws + ((size_t)8 << 20));
  unsigned short* Wp = (unsigned short*)(ws + ((size_t)12 << 20));

  pack_w<<<dim3(768), dim3(256), 0, stream>>>(Wq, Wk, Wv, Wp);
  proj_kernel<<<dim3(BT / 64), dim3(256), 0, stream>>>(x, Wp, Q, Kb, Vb);
  flash_kernel<<<dim3(512), dim3(256), 0, stream>>>(Q, Kb, Vb, out);
}

// Round 2
// 291.777 us; speedup vs baseline: 1.2725x; 1.2725x over previous
//
#include <hip/hip_runtime.h>

// Single causal attention head: B=16, T=2048, C=1024, H=64.
// pack_w: W fp32 -> bf16 Wp, layout matched to global_load_lds B-staging.
// proj:   x[32768,1024]fp32 x Wp -> Q,K row-major bf16 + Vt[b][h][t] bf16.
//         m97-style: BK=64, A: fp32 regs->cvt->ds_write_b128, B: global_load_lds(16B).
// flash:  barrier-free flash attention. K,Vt frags straight from global (L2);
//         P C->A layout transform through per-wave LDS (same-wave DS ordering,
//         no __syncthreads anywhere).
//
// MFMA 16x16x32 bf16 layouts (HW-verified):
//   A[m][k]: m = lane&15, k = (lane>>4)*8 + j
//   B[k][n]: n = lane&15, k = (lane>>4)*8 + j
//   C/D:     col = lane&15, row = (lane>>4)*4 + reg

typedef float  floatx4 __attribute__((ext_vector_type(4)));
typedef __bf16 bf16x8  __attribute__((ext_vector_type(8)));
typedef short  short8v __attribute__((ext_vector_type(8)));
typedef unsigned short ushort4v __attribute__((ext_vector_type(4)));

constexpr int Bn = 16;
constexpr int Tn = 2048;
constexpr int Cn = 1024;
constexpr int Hn = 64;
constexpr int BT = Bn * Tn;

__device__ __forceinline__ unsigned short f2b(float f) {
  unsigned int u = __builtin_bit_cast(unsigned int, f);
  u += 0x7fffu + ((u >> 16) & 1u);
  return (unsigned short)(u >> 16);
}

// ---------------------------------------------------------------------------
// Wp[ct 0..11][kb 0..127][c 0..15][j 0..7] bf16  (global col = ct*16+c, k = kb*8+j)
// ---------------------------------------------------------------------------
__global__ __launch_bounds__(256) void pack_w(const float* __restrict__ Wq,
                                              const float* __restrict__ Wk,
                                              const float* __restrict__ Wv,
                                              unsigned short* __restrict__ Wp) {
  int gid = blockIdx.x * 256 + threadIdx.x;
  int mat = gid >> 16;
  int rem = gid & 65535;
  int k   = rem >> 6;
  int col = rem & 63;
  const float* W = (mat == 0) ? Wq : (mat == 1) ? Wk : Wv;
  float v = W[rem];
  int kb = k >> 3, j = k & 7, ct = (mat << 2) | (col >> 4), c = col & 15;
  size_t idx = ((((size_t)ct * 128) + kb) * 16 + c) * 8 + j;
  Wp[idx] = f2b(v);
}

// ---------------------------------------------------------------------------
// proj: block = 256 thr (4 waves), tile 64 rows x 192 cols, BK=64.
// wave(wr,wc): rows wr*32..+31, cols wc*96..+95 (2 A-frags x 6 B-frags, 24 MFMA).
// ---------------------------------------------------------------------------
__global__ __launch_bounds__(256) void proj_kernel(
    const float* __restrict__ x, const unsigned short* __restrict__ Wp,
    unsigned short* __restrict__ Q, unsigned short* __restrict__ K,
    unsigned short* __restrict__ Vt) {
  __shared__ alignas(16) unsigned short Al[64][72];   // 9216 B, pad->2-way banks
  __shared__ alignas(16) unsigned short Bl[12 * 1024];// 24576 B, [ct][kb][c][j]

  const int tid  = threadIdx.x;
  const int wave = tid >> 6;
  const int lane = tid & 63;
  const int quad = lane >> 4;
  const int l16  = lane & 15;
  const int wr   = wave >> 1;
  const int wc   = wave & 1;
  const int rbase = blockIdx.x * 64;

  floatx4 acc[2][6];
#pragma unroll
  for (int a = 0; a < 2; ++a)
#pragma unroll
    for (int b = 0; b < 6; ++b) acc[a][b] = (floatx4){0.f, 0.f, 0.f, 0.f};

  const int arow = tid >> 2;          // 0..63
  const int acol = (tid & 3) * 16;    // 0,16,32,48
  const float* xp = x + (size_t)(rbase + arow) * Cn + acol;

  for (int k0 = 0; k0 < Cn; k0 += 64) {
    // A: 16 fp32 per thread, issued before the barrier to hide latency
    floatx4 f0 = *reinterpret_cast<const floatx4*>(xp + k0);
    floatx4 f1 = *reinterpret_cast<const floatx4*>(xp + k0 + 4);
    floatx4 f2 = *reinterpret_cast<const floatx4*>(xp + k0 + 8);
    floatx4 f3 = *reinterpret_cast<const floatx4*>(xp + k0 + 12);

    if (k0) __syncthreads();   // previous iteration done reading LDS

    // B: 6 x global_load_lds(16B) per wave; lane = kb_sub*16 + c
#pragma unroll
    for (int i = 0; i < 3; ++i) {
      const int ct = wave * 3 + i;
#pragma unroll
      for (int h = 0; h < 2; ++h) {
        const unsigned short* g =
            Wp + ((size_t)(ct * 128 + (k0 >> 3) + h * 4 + quad) * 16 + l16) * 8;
        __builtin_amdgcn_global_load_lds(
            (const __attribute__((address_space(1))) void*)g,
            (__attribute__((address_space(3))) void*)&Bl[ct * 1024 + h * 512],
            16, 0, 0);
      }
    }

    short8v p0, p1;
    p0[0] = (short)f2b(f0[0]); p0[1] = (short)f2b(f0[1]);
    p0[2] = (short)f2b(f0[2]); p0[3] = (short)f2b(f0[3]);
    p0[4] = (short)f2b(f1[0]); p0[5] = (short)f2b(f1[1]);
    p0[6] = (short)f2b(f1[2]); p0[7] = (short)f2b(f1[3]);
    p1[0] = (short)f2b(f2[0]); p1[1] = (short)f2b(f2[1]);
    p1[2] = (short)f2b(f2[2]); p1[3] = (short)f2b(f2[3]);
    p1[4] = (short)f2b(f3[0]); p1[5] = (short)f2b(f3[1]);
    p1[6] = (short)f2b(f3[2]); p1[7] = (short)f2b(f3[3]);
    *reinterpret_cast<short8v*>(&Al[arow][acol])     = p0;
    *reinterpret_cast<short8v*>(&Al[arow][acol + 8]) = p1;

    __syncthreads();

#pragma unroll
    for (int kk = 0; kk < 2; ++kk) {
      bf16x8 a0 = *reinterpret_cast<const bf16x8*>(
          &Al[wr * 32 + l16][kk * 32 + quad * 8]);
      bf16x8 a1 = *reinterpret_cast<const bf16x8*>(
          &Al[wr * 32 + 16 + l16][kk * 32 + quad * 8]);
#pragma unroll
      for (int c6 = 0; c6 < 6; ++c6) {
        const int ct = wc * 6 + c6;
        bf16x8 bfr = *reinterpret_cast<const bf16x8*>(
            &Bl[ct * 1024 + (kk * 4 + quad) * 128 + l16 * 8]);
        acc[0][c6] = __builtin_amdgcn_mfma_f32_16x16x32_bf16(a0, bfr, acc[0][c6], 0, 0, 0);
        acc[1][c6] = __builtin_amdgcn_mfma_f32_16x16x32_bf16(a1, bfr, acc[1][c6], 0, 0, 0);
      }
    }
  }

  // epilogue: Q (x0.125), K row-major; V transposed to Vt[b][h][t]
#pragma unroll
  for (int rt = 0; rt < 2; ++rt) {
#pragma unroll
    for (int c6 = 0; c6 < 6; ++c6) {
      const int cbase  = wc * 96 + c6 * 16;
      const int rowloc = wr * 32 + rt * 16 + quad * 4;
      if (cbase < 64) {
#pragma unroll
        for (int r = 0; r < 4; ++r)
          Q[(size_t)(rbase + rowloc + r) * Hn + cbase + l16] =
              f2b(acc[rt][c6][r] * 0.125f);
      } else if (cbase < 128) {
#pragma unroll
        for (int r = 0; r < 4; ++r)
          K[(size_t)(rbase + rowloc + r) * Hn + cbase - 64 + l16] =
              f2b(acc[rt][c6][r]);
      } else {
        const int b  = rbase >> 11;
        const int t0 = (rbase & 2047) + rowloc;
        const int h  = cbase - 128 + l16;
        ushort4v v;
#pragma unroll
        for (int r = 0; r < 4; ++r) v[r] = f2b(acc[rt][c6][r]);
        *reinterpret_cast<ushort4v*>(&Vt[((size_t)b * Hn + h) * Tn + t0]) = v;
      }
    }
  }
}

// ---------------------------------------------------------------------------
// flash: barrier-free. Block = 4 waves, 64 q-rows; wave owns 16 q-rows.
// ---------------------------------------------------------------------------
__global__ __launch_bounds__(256) void flash_kernel(
    const unsigned short* __restrict__ Q, const unsigned short* __restrict__ K,
    const unsigned short* __restrict__ Vt, float* __restrict__ out) {
  __shared__ alignas(16) unsigned short P[4][16][72];  // per-wave, no barriers

  const int tid  = threadIdx.x;
  const int wave = tid >> 6;
  const int lane = tid & 63;
  const int quad = lane >> 4;
  const int l16  = lane & 15;

  const int b  = blockIdx.x & 15;
  const int qt = 31 - (blockIdx.x >> 4);   // heavy tiles dispatched first
  const int qbase = qt * 64;
  const size_t bbase  = (size_t)b * Tn * Hn;   // Q,K,out
  const size_t vtbase = (size_t)b * Hn * Tn;   // Vt

  bf16x8 qf[2];
#pragma unroll
  for (int i = 0; i < 2; ++i)
    qf[i] = *reinterpret_cast<const bf16x8*>(
        &Q[bbase + (size_t)(qbase + wave * 16 + l16) * Hn + i * 32 + quad * 8]);

  floatx4 O[4];
#pragma unroll
  for (int i = 0; i < 4; ++i) O[i] = (floatx4){0.f, 0.f, 0.f, 0.f};
  float m_r[4], l_r[4];
#pragma unroll
  for (int r = 0; r < 4; ++r) { m_r[r] = -INFINITY; l_r[r] = 0.f; }

  for (int kt = 0; kt <= qt; ++kt) {
    const int kvbase = kt * 64;

    // S = Q K^T : K-frags straight from global (L2-resident)
    floatx4 S[4];
#pragma unroll
    for (int ct = 0; ct < 4; ++ct) {
      floatx4 s = (floatx4){0.f, 0.f, 0.f, 0.f};
#pragma unroll
      for (int kk = 0; kk < 2; ++kk) {
        bf16x8 bfr = *reinterpret_cast<const bf16x8*>(
            &K[bbase + (size_t)(kvbase + ct * 16 + l16) * Hn + kk * 32 + quad * 8]);
        s = __builtin_amdgcn_mfma_f32_16x16x32_bf16(qf[kk], bfr, s, 0, 0, 0);
      }
      S[ct] = s;
    }

    // prefetch V fragments while softmax VALU runs
    bf16x8 vf[4][2];
#pragma unroll
    for (int ht = 0; ht < 4; ++ht)
#pragma unroll
      for (int kk = 0; kk < 2; ++kk)
        vf[ht][kk] = *reinterpret_cast<const bf16x8*>(
            &Vt[vtbase + (size_t)(ht * 16 + l16) * Tn + kvbase + kk * 32 + quad * 8]);

    // causal mask (only bites on the diagonal tile)
    if (kt == qt) {
#pragma unroll
      for (int ct = 0; ct < 4; ++ct)
#pragma unroll
        for (int r = 0; r < 4; ++r) {
          int trow = qbase + wave * 16 + quad * 4 + r;
          int scol = kvbase + ct * 16 + l16;
          if (scol > trow) S[ct][r] = -1e30f;
        }
    }

    // online softmax, rows spread over 16 lanes
#pragma unroll
    for (int r = 0; r < 4; ++r) {
      float mx = fmaxf(fmaxf(S[0][r], S[1][r]), fmaxf(S[2][r], S[3][r]));
#pragma unroll
      for (int d = 1; d < 16; d <<= 1) mx = fmaxf(mx, __shfl_xor(mx, d));
      float mnew  = fmaxf(m_r[r], mx);
      float alpha = __expf(m_r[r] - mnew);
      float rs = 0.f;
#pragma unroll
      for (int ct = 0; ct < 4; ++ct) {
        float p = __expf(S[ct][r] - mnew);
        S[ct][r] = p;
        rs += p;
      }
#pragma unroll
      for (int d = 1; d < 16; d <<= 1) rs += __shfl_xor(rs, d);
      l_r[r] = l_r[r] * alpha + rs;
      m_r[r] = mnew;
#pragma unroll
      for (int ct = 0; ct < 4; ++ct) O[ct][r] *= alpha;
#pragma unroll
      for (int ct = 0; ct < 4; ++ct)
        P[wave][quad * 4 + r][ct * 16 + l16] = f2b(S[ct][r]);
    }

    // C->A layout transform via per-wave LDS (same-wave DS ordering: no barrier)
    bf16x8 pf0 = *reinterpret_cast<const bf16x8*>(&P[wave][l16][quad * 8]);
    bf16x8 pf1 = *reinterpret_cast<const bf16x8*>(&P[wave][l16][32 + quad * 8]);
#pragma unroll
    for (int ht = 0; ht < 4; ++ht) {
      O[ht] = __builtin_amdgcn_mfma_f32_16x16x32_bf16(pf0, vf[ht][0], O[ht], 0, 0, 0);
      O[ht] = __builtin_amdgcn_mfma_f32_16x16x32_bf16(pf1, vf[ht][1], O[ht], 0, 0, 0);
    }
  }

#pragma unroll
  for (int r = 0; r < 4; ++r) {
    float inv = 1.0f / l_r[r];
    int trow = qbase + wave * 16 + quad * 4 + r;
#pragma unroll
    for (int ht = 0; ht < 4; ++ht)
      out[bbase + (size_t)trow * Hn + ht * 16 + l16] = O[ht][r] * inv;
  }
}

// ---------------------------------------------------------------------------
extern "C" void kernel_launch(void* const* d_in, const int* in_sizes, int n_in,
                              void* d_out, int out_size, void* d_ws, size_t ws_size,
                              hipStream_t stream) {
  const float* x  = (const float*)d_in[0];
  const float* Wq = (const float*)d_in[1];
  const float* Wk = (const float*)d_in[2];
  const float* Wv = (const float*)d_in[3];
  float* out = (float*)d_out;

  char* ws = (char*)d_ws;
  // ws: Q (4MB) | K (4MB) | Vt (4MB) | Wp (384KB)
  unsigned short* Q  = (unsigned short*)(ws);
  unsigned short* Kb = (unsigned short*)(ws + ((size_t)4 << 20));
  unsigned short* Vt = (unsigned short*)(ws + ((size_t)8 << 20));
  unsigned short* Wp = (unsigned short*)(ws + ((size_t)12 << 20));

  pack_w<<<dim3(768), dim3(256), 0, stream>>>(Wq, Wk, Wv, Wp);
  proj_kernel<<<dim3(BT / 64), dim3(256), 0, stream>>>(x, Wp, Q, Kb, Vt);
  flash_kernel<<<dim3(512), dim3(256), 0, stream>>>(Q, Kb, Vt, out);
}

// Round 3
// 270.777 us; speedup vs baseline: 1.3711x; 1.0776x over previous
//
#include <hip/hip_runtime.h>

// Single causal attention head: B=16, T=2048, C=1024, H=64.
// pack_w: W fp32 -> bf16 Wp, layout matched to global_load_lds B-staging.
// proj:   x[32768,1024]fp32 x Wp -> Q,K row-major bf16 + Vt[b][h][t] bf16.
// flash:  block = 16 q-rows; 4 waves stride kv-tiles (split-kv in-block),
//         private online-softmax state per wave, 4-way (m,l,O) merge via LDS.
//         No barriers in the kv loop (per-wave P tile, same-wave DS ordering).
//
// MFMA 16x16x32 bf16 layouts (HW-verified):
//   A[m][k]: m = lane&15, k = (lane>>4)*8 + j
//   B[k][n]: n = lane&15, k = (lane>>4)*8 + j
//   C/D:     col = lane&15, row = (lane>>4)*4 + reg

typedef float  floatx4 __attribute__((ext_vector_type(4)));
typedef __bf16 bf16x8  __attribute__((ext_vector_type(8)));
typedef short  short8v __attribute__((ext_vector_type(8)));
typedef unsigned short ushort4v __attribute__((ext_vector_type(4)));

constexpr int Bn = 16;
constexpr int Tn = 2048;
constexpr int Cn = 1024;
constexpr int Hn = 64;
constexpr int BT = Bn * Tn;

__device__ __forceinline__ unsigned short f2b(float f) {
  unsigned int u = __builtin_bit_cast(unsigned int, f);
  u += 0x7fffu + ((u >> 16) & 1u);
  return (unsigned short)(u >> 16);
}

// ---------------------------------------------------------------------------
// Wp[ct 0..11][kb 0..127][c 0..15][j 0..7] bf16  (global col = ct*16+c, k = kb*8+j)
// ---------------------------------------------------------------------------
__global__ __launch_bounds__(256) void pack_w(const float* __restrict__ Wq,
                                              const float* __restrict__ Wk,
                                              const float* __restrict__ Wv,
                                              unsigned short* __restrict__ Wp) {
  int gid = blockIdx.x * 256 + threadIdx.x;
  int mat = gid >> 16;
  int rem = gid & 65535;
  int k   = rem >> 6;
  int col = rem & 63;
  const float* W = (mat == 0) ? Wq : (mat == 1) ? Wk : Wv;
  float v = W[rem];
  int kb = k >> 3, j = k & 7, ct = (mat << 2) | (col >> 4), c = col & 15;
  size_t idx = ((((size_t)ct * 128) + kb) * 16 + c) * 8 + j;
  Wp[idx] = f2b(v);
}

// ---------------------------------------------------------------------------
// proj: block = 256 thr (4 waves), tile 64 rows x 192 cols, BK=64.
// ---------------------------------------------------------------------------
__global__ __launch_bounds__(256) void proj_kernel(
    const float* __restrict__ x, const unsigned short* __restrict__ Wp,
    unsigned short* __restrict__ Q, unsigned short* __restrict__ K,
    unsigned short* __restrict__ Vt) {
  __shared__ alignas(16) unsigned short Al[64][72];
  __shared__ alignas(16) unsigned short Bl[12 * 1024];

  const int tid  = threadIdx.x;
  const int wave = tid >> 6;
  const int lane = tid & 63;
  const int quad = lane >> 4;
  const int l16  = lane & 15;
  const int wr   = wave >> 1;
  const int wc   = wave & 1;
  const int rbase = blockIdx.x * 64;

  floatx4 acc[2][6];
#pragma unroll
  for (int a = 0; a < 2; ++a)
#pragma unroll
    for (int b = 0; b < 6; ++b) acc[a][b] = (floatx4){0.f, 0.f, 0.f, 0.f};

  const int arow = tid >> 2;
  const int acol = (tid & 3) * 16;
  const float* xp = x + (size_t)(rbase + arow) * Cn + acol;

  for (int k0 = 0; k0 < Cn; k0 += 64) {
    floatx4 f0 = *reinterpret_cast<const floatx4*>(xp + k0);
    floatx4 f1 = *reinterpret_cast<const floatx4*>(xp + k0 + 4);
    floatx4 f2 = *reinterpret_cast<const floatx4*>(xp + k0 + 8);
    floatx4 f3 = *reinterpret_cast<const floatx4*>(xp + k0 + 12);

    if (k0) __syncthreads();

#pragma unroll
    for (int i = 0; i < 3; ++i) {
      const int ct = wave * 3 + i;
#pragma unroll
      for (int h = 0; h < 2; ++h) {
        const unsigned short* g =
            Wp + ((size_t)(ct * 128 + (k0 >> 3) + h * 4 + quad) * 16 + l16) * 8;
        __builtin_amdgcn_global_load_lds(
            (const __attribute__((address_space(1))) void*)g,
            (__attribute__((address_space(3))) void*)&Bl[ct * 1024 + h * 512],
            16, 0, 0);
      }
    }

    short8v p0, p1;
    p0[0] = (short)f2b(f0[0]); p0[1] = (short)f2b(f0[1]);
    p0[2] = (short)f2b(f0[2]); p0[3] = (short)f2b(f0[3]);
    p0[4] = (short)f2b(f1[0]); p0[5] = (short)f2b(f1[1]);
    p0[6] = (short)f2b(f1[2]); p0[7] = (short)f2b(f1[3]);
    p1[0] = (short)f2b(f2[0]); p1[1] = (short)f2b(f2[1]);
    p1[2] = (short)f2b(f2[2]); p1[3] = (short)f2b(f2[3]);
    p1[4] = (short)f2b(f3[0]); p1[5] = (short)f2b(f3[1]);
    p1[6] = (short)f2b(f3[2]); p1[7] = (short)f2b(f3[3]);
    *reinterpret_cast<short8v*>(&Al[arow][acol])     = p0;
    *reinterpret_cast<short8v*>(&Al[arow][acol + 8]) = p1;

    __syncthreads();

#pragma unroll
    for (int kk = 0; kk < 2; ++kk) {
      bf16x8 a0 = *reinterpret_cast<const bf16x8*>(
          &Al[wr * 32 + l16][kk * 32 + quad * 8]);
      bf16x8 a1 = *reinterpret_cast<const bf16x8*>(
          &Al[wr * 32 + 16 + l16][kk * 32 + quad * 8]);
#pragma unroll
      for (int c6 = 0; c6 < 6; ++c6) {
        const int ct = wc * 6 + c6;
        bf16x8 bfr = *reinterpret_cast<const bf16x8*>(
            &Bl[ct * 1024 + (kk * 4 + quad) * 128 + l16 * 8]);
        acc[0][c6] = __builtin_amdgcn_mfma_f32_16x16x32_bf16(a0, bfr, acc[0][c6], 0, 0, 0);
        acc[1][c6] = __builtin_amdgcn_mfma_f32_16x16x32_bf16(a1, bfr, acc[1][c6], 0, 0, 0);
      }
    }
  }

#pragma unroll
  for (int rt = 0; rt < 2; ++rt) {
#pragma unroll
    for (int c6 = 0; c6 < 6; ++c6) {
      const int cbase  = wc * 96 + c6 * 16;
      const int rowloc = wr * 32 + rt * 16 + quad * 4;
      if (cbase < 64) {
#pragma unroll
        for (int r = 0; r < 4; ++r)
          Q[(size_t)(rbase + rowloc + r) * Hn + cbase + l16] =
              f2b(acc[rt][c6][r] * 0.125f);
      } else if (cbase < 128) {
#pragma unroll
        for (int r = 0; r < 4; ++r)
          K[(size_t)(rbase + rowloc + r) * Hn + cbase - 64 + l16] =
              f2b(acc[rt][c6][r]);
      } else {
        const int b  = rbase >> 11;
        const int t0 = (rbase & 2047) + rowloc;
        const int h  = cbase - 128 + l16;
        ushort4v v;
#pragma unroll
        for (int r = 0; r < 4; ++r) v[r] = f2b(acc[rt][c6][r]);
        *reinterpret_cast<ushort4v*>(&Vt[((size_t)b * Hn + h) * Tn + t0]) = v;
      }
    }
  }
}

// ---------------------------------------------------------------------------
// flash: block = 256 thr = 4 waves, 16 q-rows. Wave w handles kv tiles
// kt = w, w+4, ... (private m/l/O), then 4-way merge through LDS.
// ---------------------------------------------------------------------------
__global__ __launch_bounds__(256) void flash_kernel(
    const unsigned short* __restrict__ Q, const unsigned short* __restrict__ K,
    const unsigned short* __restrict__ Vt, float* __restrict__ out) {
  __shared__ alignas(16) unsigned short P[4][16][72];  // per-wave scratch
  __shared__ alignas(16) float Om[4][16][68];          // merge: O partials
  __shared__ float Ml[4][16][2];                       // merge: m,l partials

  const int tid  = threadIdx.x;
  const int wave = tid >> 6;
  const int lane = tid & 63;
  const int quad = lane >> 4;
  const int l16  = lane & 15;

  const int b   = blockIdx.x & 15;
  const int p16 = 127 - (blockIdx.x >> 4);   // heavy q-subtiles first
  const int qbase = p16 * 16;
  const int n_tiles  = (p16 >> 2) + 1;       // kv tiles of 64 needed
  const int lastTile = p16 >> 2;
  const size_t bbase  = (size_t)b * Tn * Hn;
  const size_t vtbase = (size_t)b * Hn * Tn;

  bf16x8 qf[2];
#pragma unroll
  for (int i = 0; i < 2; ++i)
    qf[i] = *reinterpret_cast<const bf16x8*>(
        &Q[bbase + (size_t)(qbase + l16) * Hn + i * 32 + quad * 8]);

  floatx4 O[4];
#pragma unroll
  for (int i = 0; i < 4; ++i) O[i] = (floatx4){0.f, 0.f, 0.f, 0.f};
  float m_r[4], l_r[4];
#pragma unroll
  for (int r = 0; r < 4; ++r) { m_r[r] = -INFINITY; l_r[r] = 0.f; }

  for (int kt = wave; kt < n_tiles; kt += 4) {
    const int kvbase = kt * 64;

    // S = Q K^T : K-frags straight from global (L2-resident)
    floatx4 S[4];
#pragma unroll
    for (int ct = 0; ct < 4; ++ct) {
      floatx4 s = (floatx4){0.f, 0.f, 0.f, 0.f};
#pragma unroll
      for (int kk = 0; kk < 2; ++kk) {
        bf16x8 bfr = *reinterpret_cast<const bf16x8*>(
            &K[bbase + (size_t)(kvbase + ct * 16 + l16) * Hn + kk * 32 + quad * 8]);
        s = __builtin_amdgcn_mfma_f32_16x16x32_bf16(qf[kk], bfr, s, 0, 0, 0);
      }
      S[ct] = s;
    }

    // prefetch V fragments while softmax VALU runs
    bf16x8 vf[4][2];
#pragma unroll
    for (int ht = 0; ht < 4; ++ht)
#pragma unroll
      for (int kk = 0; kk < 2; ++kk)
        vf[ht][kk] = *reinterpret_cast<const bf16x8*>(
            &Vt[vtbase + (size_t)(ht * 16 + l16) * Tn + kvbase + kk * 32 + quad * 8]);

    // causal mask — only the globally-last tile can cross the diagonal
    if (kt == lastTile) {
#pragma unroll
      for (int ct = 0; ct < 4; ++ct)
#pragma unroll
        for (int r = 0; r < 4; ++r) {
          int trow = qbase + quad * 4 + r;
          int scol = kvbase + ct * 16 + l16;
          if (scol > trow) S[ct][r] = -1e30f;
        }
    }

    // online softmax (row = quad*4+r, spread over 16 lanes)
#pragma unroll
    for (int r = 0; r < 4; ++r) {
      float mx = fmaxf(fmaxf(S[0][r], S[1][r]), fmaxf(S[2][r], S[3][r]));
#pragma unroll
      for (int d = 1; d < 16; d <<= 1) mx = fmaxf(mx, __shfl_xor(mx, d));
      float mnew  = fmaxf(m_r[r], mx);
      float alpha = __expf(m_r[r] - mnew);
      float rs = 0.f;
#pragma unroll
      for (int ct = 0; ct < 4; ++ct) {
        float p = __expf(S[ct][r] - mnew);
        S[ct][r] = p;
        rs += p;
      }
#pragma unroll
      for (int d = 1; d < 16; d <<= 1) rs += __shfl_xor(rs, d);
      l_r[r] = l_r[r] * alpha + rs;
      m_r[r] = mnew;
#pragma unroll
      for (int ct = 0; ct < 4; ++ct) O[ct][r] *= alpha;
#pragma unroll
      for (int ct = 0; ct < 4; ++ct)
        P[wave][quad * 4 + r][ct * 16 + l16] = f2b(S[ct][r]);
    }

    // C->A transform via per-wave LDS (same-wave DS ordering: no barrier)
    bf16x8 pf0 = *reinterpret_cast<const bf16x8*>(&P[wave][l16][quad * 8]);
    bf16x8 pf1 = *reinterpret_cast<const bf16x8*>(&P[wave][l16][32 + quad * 8]);
#pragma unroll
    for (int ht = 0; ht < 4; ++ht) {
      O[ht] = __builtin_amdgcn_mfma_f32_16x16x32_bf16(pf0, vf[ht][0], O[ht], 0, 0, 0);
      O[ht] = __builtin_amdgcn_mfma_f32_16x16x32_bf16(pf1, vf[ht][1], O[ht], 0, 0, 0);
    }
  }

  // ---- 4-way merge across waves ----
#pragma unroll
  for (int ht = 0; ht < 4; ++ht)
#pragma unroll
    for (int r = 0; r < 4; ++r)
      Om[wave][quad * 4 + r][ht * 16 + l16] = O[ht][r];
  if (l16 == 0) {
#pragma unroll
    for (int r = 0; r < 4; ++r) {
      Ml[wave][quad * 4 + r][0] = m_r[r];
      Ml[wave][quad * 4 + r][1] = l_r[r];
    }
  }
  __syncthreads();

  {
    const int row = tid >> 4;           // 0..15
    const int c4  = (tid & 15) * 4;     // 0,4,..,60
    float m0 = Ml[0][row][0], m1 = Ml[1][row][0];
    float m2 = Ml[2][row][0], m3 = Ml[3][row][0];
    float M = fmaxf(fmaxf(m0, m1), fmaxf(m2, m3));
    float e0 = __expf(m0 - M), e1 = __expf(m1 - M);
    float e2 = __expf(m2 - M), e3 = __expf(m3 - M);
    float L = Ml[0][row][1] * e0 + Ml[1][row][1] * e1 +
              Ml[2][row][1] * e2 + Ml[3][row][1] * e3;
    float invL = 1.0f / L;
    floatx4 o0 = *reinterpret_cast<const floatx4*>(&Om[0][row][c4]);
    floatx4 o1 = *reinterpret_cast<const floatx4*>(&Om[1][row][c4]);
    floatx4 o2 = *reinterpret_cast<const floatx4*>(&Om[2][row][c4]);
    floatx4 o3 = *reinterpret_cast<const floatx4*>(&Om[3][row][c4]);
    floatx4 res;
#pragma unroll
    for (int j = 0; j < 4; ++j)
      res[j] = (o0[j] * e0 + o1[j] * e1 + o2[j] * e2 + o3[j] * e3) * invL;
    *reinterpret_cast<floatx4*>(
        &out[bbase + (size_t)(qbase + row) * Hn + c4]) = res;
  }
}

// ---------------------------------------------------------------------------
extern "C" void kernel_launch(void* const* d_in, const int* in_sizes, int n_in,
                              void* d_out, int out_size, void* d_ws, size_t ws_size,
                              hipStream_t stream) {
  const float* x  = (const float*)d_in[0];
  const float* Wq = (const float*)d_in[1];
  const float* Wk = (const float*)d_in[2];
  const float* Wv = (const float*)d_in[3];
  float* out = (float*)d_out;

  char* ws = (char*)d_ws;
  unsigned short* Q  = (unsigned short*)(ws);
  unsigned short* Kb = (unsigned short*)(ws + ((size_t)4 << 20));
  unsigned short* Vt = (unsigned short*)(ws + ((size_t)8 << 20));
  unsigned short* Wp = (unsigned short*)(ws + ((size_t)12 << 20));

  pack_w<<<dim3(768), dim3(256), 0, stream>>>(Wq, Wk, Wv, Wp);
  proj_kernel<<<dim3(BT / 64), dim3(256), 0, stream>>>(x, Wp, Q, Kb, Vt);
  flash_kernel<<<dim3(16 * 128), dim3(256), 0, stream>>>(Q, Kb, Vt, out);
}